// Round 7
// baseline (1349.611 us; speedup 1.0000x reference)
//
#include <hip/hip_runtime.h>
#include <hip/hip_bf16.h>

#define B_    16
#define C_    96
#define H_    224
#define W_    224
#define COUT_ 96
#define GH_   14
#define GW_   14
#define P_    196          // GH_*GW_
#define HW_   (H_*W_)      // 50176
#define NCH_  12           // 8-channel chunks

typedef __attribute__((ext_vector_type(8))) unsigned short ushort8;
typedef __attribute__((ext_vector_type(8))) short        short8;   // MFMA bf16x8 operand
typedef __attribute__((ext_vector_type(4))) float        f32x4;

__device__ __forceinline__ unsigned short f2bf(float f) {
    union { __hip_bfloat16 h; unsigned short u; } cv;
    cv.h = __float2bfloat16(f);
    return cv.u;
}

// ---------------------------------------------------------------------------
// Kernel 0: output_filters (COUT, C, 3, 3) f32 -> ofb[tap][cout][c] bf16
// ---------------------------------------------------------------------------
__global__ __launch_bounds__(256) void prep_ofb(const float* __restrict__ of,
                                                unsigned short* __restrict__ ofb) {
    int idx = blockIdx.x * 256 + threadIdx.x;      // 9*96*96 = 82944
    if (idx < 9 * 96 * 96) {
        int tap = idx / (96 * 96);
        int r   = idx % (96 * 96);
        int cout = r / 96, c = r % 96;
        ofb[idx] = f2bf(of[((size_t)cout * 96 + c) * 9 + tap]);
    }
}

// ---------------------------------------------------------------------------
// Kernel 1: per-patch depthwise 3x3 (patch-local zero padding).
// x: (B,C,H,W) f32 -> sa: (B, 12, H, W, 8) bf16  (8-ch chunk planes).
// (R5-proven: ~107 us. Unchanged.)
// ---------------------------------------------------------------------------
__global__ __launch_bounds__(256) void sa_kernel(const float* __restrict__ x,
                                                 const float* __restrict__ pf,
                                                 unsigned short* __restrict__ sa) {
    int bid   = blockIdx.x;
    int patch = bid % P_;
    int b     = bid / P_;
    int gh = patch / GW_, gw = patch % GW_;
    int t  = threadIdx.x;
    int py = t >> 4, px = t & 15;
    int y  = gh * 16 + py, xx = gw * 16 + px;

    __shared__ float xs[2][8][256];    // 16 KB double-buffered x slice

    const float* xp0 = x + (size_t)b * C_ * HW_ + (size_t)y * W_ + xx;

    float lf[8];
    #pragma unroll
    for (int ch = 0; ch < 8; ++ch) lf[ch] = xp0[(size_t)ch * HW_];

    for (int cc = 0; cc < NCH_; ++cc) {
        int buf = cc & 1;
        #pragma unroll
        for (int ch = 0; ch < 8; ++ch) xs[buf][ch][t] = lf[ch];
        __syncthreads();
        if (cc < NCH_ - 1) {
            #pragma unroll
            for (int ch = 0; ch < 8; ++ch)
                lf[ch] = xp0[(size_t)((cc + 1) * 8 + ch) * HW_];
        }

        ushort8 v;
        #pragma unroll
        for (int ch = 0; ch < 8; ++ch) {
            const float* wgt = pf + ((size_t)(cc * 8 + ch) * P_ + patch) * 9;  // uniform -> s_load
            float a = 0.f;
            #pragma unroll
            for (int dy = -1; dy <= 1; ++dy) {
                int yy = py + dy;
                if ((unsigned)yy < 16u) {
                    #pragma unroll
                    for (int dx = -1; dx <= 1; ++dx) {
                        int xq = px + dx;
                        if ((unsigned)xq < 16u)
                            a = fmaf(xs[buf][ch][yy * 16 + xq],
                                     wgt[(dy + 1) * 3 + (dx + 1)], a);
                    }
                }
            }
            v[ch] = f2bf(a);
        }
        // lanes consecutive in x -> 16 B/lane fully coalesced
        *(ushort8*)&sa[(((size_t)(b * NCH_ + cc) * H_ + y) * W_ + xx) * 8] = v;
    }
}

// ---------------------------------------------------------------------------
// Kernel 2: dense 3x3 conv as implicit GEMM (M=256 px, N=96, K=864) + GELU.
// R7: SINGLE-buffered 26 KB tile (stride-40 padding kept) -> 4 blocks/CU;
// LOADG(g+1) issued before the MFMA window so loads fly across it; TLP
// (16 waves/CU) hides B-load + LDS latency instead of intra-block dbuf.
// ---------------------------------------------------------------------------
__global__ __launch_bounds__(256, 4) void conv2_mfma(const unsigned short* __restrict__ sa,
                                                     const unsigned short* __restrict__ ofb,
                                                     float* __restrict__ out) {
    // XCD-aware swizzle (3136 % 8 == 0 -> bijective)
    int bid0 = blockIdx.x;
    int bid  = (bid0 % 8) * (3136 / 8) + bid0 / 8;
    int patch = bid % P_;
    int b     = bid / P_;
    int gh = patch / GW_, gw = patch % GW_;
    int y0 = gh * 16, x0 = gw * 16;

    int t = threadIdx.x;
    int w = t >> 6, l = t & 63;
    int mrow = l & 15, kgrp = l >> 4;

    __shared__ ushort8 at8[1620];           // 324 px x 40 ushort = 25,920 B

    ushort8 r[6];                           // staged tile in flight (24 VGPR)

    auto LOADG = [&](int g) {
        #pragma unroll
        for (int i = 0; i < 6; ++i) {
            int v = t + i * 256;            // 1296 tasks = 4 chunk-planes x 324 px
            if (v < 1296) {
                int ccl = v / 324, hpx = v % 324;
                int gy = y0 - 1 + hpx / 18, gx = x0 - 1 + hpx % 18;
                ushort8 val = {0, 0, 0, 0, 0, 0, 0, 0};
                if ((unsigned)gy < (unsigned)H_ && (unsigned)gx < (unsigned)W_)
                    val = *(const ushort8*)&sa[(((size_t)(b * NCH_ + g * 4 + ccl) * H_ + gy)
                                               * W_ + gx) * 8];
                r[i] = val;
            }
        }
    };
    auto WRITEG = [&]() {
        unsigned short* atw = (unsigned short*)at8;
        #pragma unroll
        for (int i = 0; i < 6; ++i) {
            int v = t + i * 256;
            if (v < 1296) {
                int ccl = v / 324, hpx = v % 324;
                *(ushort8*)&atw[hpx * 40 + ccl * 8] = r[i];
            }
        }
    };

    f32x4 acc[4][6];
    #pragma unroll
    for (int mi = 0; mi < 4; ++mi)
        #pragma unroll
        for (int ni = 0; ni < 6; ++ni)
            acc[mi][ni] = (f32x4)0.f;

    LOADG(0);
    WRITEG();                               // auto-waits vmcnt
    __syncthreads();                        // tile 0 visible

    #pragma unroll 1
    for (int g = 0; g < 3; ++g) {
        if (g < 2) LOADG(g + 1);            // loads in flight across MFMA window
        const unsigned short* atg = (const unsigned short*)at8;

        #pragma unroll                      // 216-MFMA scheduling window
        for (int tap = 0; tap < 9; ++tap) {
            int ky = tap / 3, kx = tap % 3;
            short8 af[4];
            #pragma unroll
            for (int mi = 0; mi < 4; ++mi)
                af[mi] = *(const short8*)&atg[((w * 4 + mi + ky) * 18 + kx + mrow) * 40
                                              + kgrp * 8];
            const unsigned short* bofs = ofb + tap * (96 * 96) + g * 32 + kgrp * 8;
            #pragma unroll
            for (int ni = 0; ni < 6; ++ni) {
                short8 bf = *(const short8*)&bofs[(ni * 16 + mrow) * 96];
                #pragma unroll
                for (int mi = 0; mi < 4; ++mi)
                    acc[mi][ni] = __builtin_amdgcn_mfma_f32_16x16x32_bf16(
                        af[mi], bf, acc[mi][ni], 0, 0, 0);
            }
        }

        if (g < 2) {
            __syncthreads();                // all waves done reading tile g
            WRITEG();                       // stage tile g+1
            __syncthreads();                // visible
        }
    }

    // ---- epilogue: exact GELU + f32x4 stores ----
    #pragma unroll
    for (int mi = 0; mi < 4; ++mi) {
        int gy = y0 + w * 4 + mi;
        #pragma unroll
        for (int ni = 0; ni < 6; ++ni) {
            int cout = ni * 16 + mrow;
            f32x4 gv;
            #pragma unroll
            for (int j = 0; j < 4; ++j) {
                float vv = acc[mi][ni][j];
                gv[j] = 0.5f * vv * (1.0f + erff(vv * 0.70710678118f));
            }
            *(f32x4*)&out[((size_t)b * COUT_ + cout) * HW_ + (size_t)gy * W_ +
                          x0 + kgrp * 4] = gv;
        }
    }
}

extern "C" void kernel_launch(void* const* d_in, const int* in_sizes, int n_in,
                              void* d_out, int out_size, void* d_ws, size_t ws_size,
                              hipStream_t stream) {
    const float* x  = (const float*)d_in[0];
    const float* pf = (const float*)d_in[1];
    const float* of = (const float*)d_in[2];
    float* out = (float*)d_out;

    unsigned short* sa  = (unsigned short*)d_ws;                       // 154,140,672 B
    unsigned short* ofb = (unsigned short*)((char*)d_ws + 154140672);  // + 165,888 B

    prep_ofb<<<324, 256, 0, stream>>>(of, ofb);
    sa_kernel<<<B_ * P_, 256, 0, stream>>>(x, pf, sa);
    conv2_mfma<<<B_ * P_, 256, 0, stream>>>(sa, ofb, out);
}

// Round 8
// 752.917 us; speedup vs baseline: 1.7925x; 1.7925x over previous
//
#include <hip/hip_runtime.h>
#include <hip/hip_bf16.h>

#define B_    16
#define C_    96
#define H_    224
#define W_    224
#define COUT_ 96
#define GH_   14
#define GW_   14
#define P_    196          // GH_*GW_
#define HW_   (H_*W_)      // 50176
#define NCH_  12           // 8-channel chunks

typedef __attribute__((ext_vector_type(8))) unsigned short ushort8;
typedef __attribute__((ext_vector_type(8))) short        short8;   // MFMA bf16x8 operand
typedef __attribute__((ext_vector_type(4))) float        f32x4;

__device__ __forceinline__ unsigned short f2bf(float f) {
    union { __hip_bfloat16 h; unsigned short u; } cv;
    cv.h = __float2bfloat16(f);
    return cv.u;
}

// ---------------------------------------------------------------------------
// Kernel 0: output_filters (COUT,C,3,3) f32 -> ofb[g][tap][cout][32ch] bf16
// so each (g,tap) B-tile is one contiguous 6144 B block.
// ---------------------------------------------------------------------------
__global__ __launch_bounds__(256) void prep_ofb(const float* __restrict__ of,
                                                unsigned short* __restrict__ ofb) {
    int idx = blockIdx.x * 256 + threadIdx.x;      // 27*96*32 = 82944
    if (idx < 27 * 96 * 32) {
        int T  = idx / (96 * 32);                  // g*9 + tap
        int r  = idx % (96 * 32);
        int cout = r / 32, cl = r % 32;
        int g = T / 9, tap = T % 9;
        ofb[idx] = f2bf(of[((size_t)cout * 96 + g * 32 + cl) * 9 + tap]);
    }
}

// ---------------------------------------------------------------------------
// Kernel 1: per-patch depthwise 3x3 (patch-local zero padding).
// x: (B,C,H,W) f32 -> sa: (B, 12, H, W, 8) bf16  (8-ch chunk planes).
// (R5-proven: ~107 us. Unchanged.)
// ---------------------------------------------------------------------------
__global__ __launch_bounds__(256) void sa_kernel(const float* __restrict__ x,
                                                 const float* __restrict__ pf,
                                                 unsigned short* __restrict__ sa) {
    int bid   = blockIdx.x;
    int patch = bid % P_;
    int b     = bid / P_;
    int gh = patch / GW_, gw = patch % GW_;
    int t  = threadIdx.x;
    int py = t >> 4, px = t & 15;
    int y  = gh * 16 + py, xx = gw * 16 + px;

    __shared__ float xs[2][8][256];    // 16 KB double-buffered x slice

    const float* xp0 = x + (size_t)b * C_ * HW_ + (size_t)y * W_ + xx;

    float lf[8];
    #pragma unroll
    for (int ch = 0; ch < 8; ++ch) lf[ch] = xp0[(size_t)ch * HW_];

    for (int cc = 0; cc < NCH_; ++cc) {
        int buf = cc & 1;
        #pragma unroll
        for (int ch = 0; ch < 8; ++ch) xs[buf][ch][t] = lf[ch];
        __syncthreads();
        if (cc < NCH_ - 1) {
            #pragma unroll
            for (int ch = 0; ch < 8; ++ch)
                lf[ch] = xp0[(size_t)((cc + 1) * 8 + ch) * HW_];
        }

        ushort8 v;
        #pragma unroll
        for (int ch = 0; ch < 8; ++ch) {
            const float* wgt = pf + ((size_t)(cc * 8 + ch) * P_ + patch) * 9;  // uniform -> s_load
            float a = 0.f;
            #pragma unroll
            for (int dy = -1; dy <= 1; ++dy) {
                int yy = py + dy;
                if ((unsigned)yy < 16u) {
                    #pragma unroll
                    for (int dx = -1; dx <= 1; ++dx) {
                        int xq = px + dx;
                        if ((unsigned)xq < 16u)
                            a = fmaf(xs[buf][ch][yy * 16 + xq],
                                     wgt[(dy + 1) * 3 + (dx + 1)], a);
                    }
                }
            }
            v[ch] = f2bf(a);
        }
        *(ushort8*)&sa[(((size_t)(b * NCH_ + cc) * H_ + y) * W_ + xx) * 8] = v;
    }
}

// ---------------------------------------------------------------------------
// Kernel 2: implicit-GEMM MFMA conv (M=256 px, N=96, K=864) + exact GELU.
// R8: both operands LDS-fed.
//   A: 18x18 halo, 4 planes [ccl][324] ushort8, 20736 B, single buffer,
//      reg-prefetched one GROUP ahead (r[6], proven R6/R7 path).
//   B: per-(g,tap) 96x32 tile, padded rows (36 ushorts) for 2-way banks,
//      TRIPLE-buffered ring (3 x 6912 B) -> one barrier per tap,
//      reg-prefetched one TAP ahead.
// LDS 41472 B, launch_bounds(256,3): 3 blocks/CU, VGPR cap 170 (no spill).
// ---------------------------------------------------------------------------
__global__ __launch_bounds__(256, 3) void conv2_mfma(const unsigned short* __restrict__ sa,
                                                     const unsigned short* __restrict__ ofb,
                                                     float* __restrict__ out) {
    // XCD-aware swizzle (3136 % 8 == 0 -> bijective)
    int bid0 = blockIdx.x;
    int bid  = (bid0 % 8) * (3136 / 8) + bid0 / 8;
    int patch = bid % P_;
    int b     = bid / P_;
    int gh = patch / GW_, gw = patch % GW_;
    int y0 = gh * 16, x0 = gw * 16;

    int t = threadIdx.x;
    int w = t >> 6, l = t & 63;
    int mrow = l & 15, kgrp = l >> 4;

    __shared__ ushort8 at8[1296];            // A: 4 planes x 324 px x 16 B = 20736 B
    __shared__ unsigned short bt[3 * 3456];  // B: 3 bufs x 96 couts x 36 (32+4 pad) = 20736 B

    ushort8 rA[6];                           // A prefetch (24 VGPR)
    ushort8 rB0, rB1;                        // B prefetch (8 VGPR)

    auto LOADG = [&](int g) {
        #pragma unroll
        for (int i = 0; i < 6; ++i) {
            int v = t + i * 256;             // 1296 = 4 planes x 324 px
            if (v < 1296) {
                int ccl = v / 324, hpx = v % 324;
                int gy = y0 - 1 + hpx / 18, gx = x0 - 1 + hpx % 18;
                ushort8 val = {0, 0, 0, 0, 0, 0, 0, 0};
                if ((unsigned)gy < (unsigned)H_ && (unsigned)gx < (unsigned)W_)
                    val = *(const ushort8*)&sa[(((size_t)(b * NCH_ + g * 4 + ccl) * H_ + gy)
                                               * W_ + gx) * 8];
                rA[i] = val;
            }
        }
    };
    auto WRITEG = [&]() {
        #pragma unroll
        for (int i = 0; i < 6; ++i) {
            int v = t + i * 256;
            if (v < 1296) at8[v] = rA[i];    // linear dest, conflict-free
        }
    };
    auto LOADB = [&](int T) {                // T = g*9+tap, tile = 384 x 16 B chunks
        const unsigned short* src = ofb + (size_t)T * 3072;
        rB0 = *(const ushort8*)&src[t * 8];
        if (t < 128) rB1 = *(const ushort8*)&src[(t + 256) * 8];
    };
    auto WRITEB = [&](int slot) {
        unsigned short* bw = bt + slot * 3456;
        *(ushort8*)&bw[(t >> 2) * 36 + (t & 3) * 8] = rB0;
        if (t < 128) {
            int c2 = t + 256;
            *(ushort8*)&bw[(c2 >> 2) * 36 + (c2 & 3) * 8] = rB1;
        }
    };

    f32x4 acc[4][6];
    #pragma unroll
    for (int mi = 0; mi < 4; ++mi)
        #pragma unroll
        for (int ni = 0; ni < 6; ++ni)
            acc[mi][ni] = (f32x4)0.f;

    // ---- prologue: A(g0) + B(T0) staged; B(T1), A(g1) prefetched ----
    LOADG(0);
    LOADB(0);
    WRITEG();
    WRITEB(0);
    LOADB(1);
    LOADG(1);
    __syncthreads();

    const unsigned short* at = (const unsigned short*)at8;

    #pragma unroll 1
    for (int g = 0; g < 3; ++g) {
        #pragma unroll
        for (int tap = 0; tap < 9; ++tap) {
            int T = g * 9 + tap;
            int ky = tap / 3, kx = tap % 3;

            // MFMA(T): A from planes, B from ring buf tap%3
            short8 af[4];
            #pragma unroll
            for (int mi = 0; mi < 4; ++mi)
                af[mi] = *(const short8*)&at[(kgrp * 324 + (w * 4 + mi + ky) * 18
                                             + kx + mrow) * 8];
            const unsigned short* bbuf = bt + (tap % 3) * 3456;
            #pragma unroll
            for (int ni = 0; ni < 6; ++ni) {
                short8 bf = *(const short8*)&bbuf[(ni * 16 + mrow) * 36 + kgrp * 8];
                #pragma unroll
                for (int mi = 0; mi < 4; ++mi)
                    acc[mi][ni] = __builtin_amdgcn_mfma_f32_16x16x32_bf16(
                        af[mi], bf, acc[mi][ni], 0, 0, 0);
            }

            // stage B(T+1) (WAR-safe: slot (tap+1)%3 last read at T-2, >=1 barrier ago)
            if (T + 1 < 27) WRITEB((tap + 1) % 3);
            if (T + 2 < 27) LOADB(T + 2);
            if (tap < 8) __syncthreads();     // publish B(T+1)
        }
        // group boundary: all A reads done; swap A tile
        __syncthreads();                      // also publishes B(T+1)
        if (g < 2) {
            WRITEG();                         // rA(g+1) -> LDS (auto vmcnt wait)
            if (g == 0) LOADG(2);             // in flight across whole group 1
            __syncthreads();                  // publish A(g+1)
        }
    }

    // ---- epilogue: exact GELU + f32x4 stores ----
    #pragma unroll
    for (int mi = 0; mi < 4; ++mi) {
        int gy = y0 + w * 4 + mi;
        #pragma unroll
        for (int ni = 0; ni < 6; ++ni) {
            int cout = ni * 16 + mrow;
            f32x4 gv;
            #pragma unroll
            for (int j = 0; j < 4; ++j) {
                float vv = acc[mi][ni][j];
                gv[j] = 0.5f * vv * (1.0f + erff(vv * 0.70710678118f));
            }
            *(f32x4*)&out[((size_t)b * COUT_ + cout) * HW_ + (size_t)gy * W_ +
                          x0 + kgrp * 4] = gv;
        }
    }
}

extern "C" void kernel_launch(void* const* d_in, const int* in_sizes, int n_in,
                              void* d_out, int out_size, void* d_ws, size_t ws_size,
                              hipStream_t stream) {
    const float* x  = (const float*)d_in[0];
    const float* pf = (const float*)d_in[1];
    const float* of = (const float*)d_in[2];
    float* out = (float*)d_out;

    unsigned short* sa  = (unsigned short*)d_ws;                       // 154,140,672 B
    unsigned short* ofb = (unsigned short*)((char*)d_ws + 154140672);  // + 165,888 B

    prep_ofb<<<324, 256, 0, stream>>>(of, ofb);
    sa_kernel<<<B_ * P_, 256, 0, stream>>>(x, pf, sa);
    conv2_mfma<<<B_ * P_, 256, 0, stream>>>(sa, ofb, out);
}

// Round 9
// 534.311 us; speedup vs baseline: 2.5259x; 1.4091x over previous
//
#include <hip/hip_runtime.h>
#include <hip/hip_bf16.h>

#define B_    16
#define C_    96
#define H_    224
#define W_    224
#define COUT_ 96
#define GH_   14
#define GW_   14
#define P_    196          // GH_*GW_
#define HW_   (H_*W_)      // 50176
#define NCH_  12           // 8-channel chunks

typedef __attribute__((ext_vector_type(8))) unsigned short ushort8;
typedef __attribute__((ext_vector_type(8))) short        short8;   // MFMA bf16x8 operand
typedef __attribute__((ext_vector_type(4))) float        f32x4;

__device__ __forceinline__ unsigned short f2bf(float f) {
    union { __hip_bfloat16 h; unsigned short u; } cv;
    cv.h = __float2bfloat16(f);
    return cv.u;
}

// ---------------------------------------------------------------------------
// Kernel 0: output_filters (COUT, C, 3, 3) f32 -> ofb[tap][cout][c] bf16
// (R6 layout: B-fragment = one contiguous ushort8 at [tap][cout][c0])
// ---------------------------------------------------------------------------
__global__ __launch_bounds__(256) void prep_ofb(const float* __restrict__ of,
                                                unsigned short* __restrict__ ofb) {
    int idx = blockIdx.x * 256 + threadIdx.x;      // 9*96*96 = 82944
    if (idx < 9 * 96 * 96) {
        int tap = idx / (96 * 96);
        int r   = idx % (96 * 96);
        int cout = r / 96, c = r % 96;
        ofb[idx] = f2bf(of[((size_t)cout * 96 + c) * 9 + tap]);
    }
}

// ---------------------------------------------------------------------------
// Kernel 1: per-patch depthwise 3x3 (patch-local zero padding).
// x: (B,C,H,W) f32 -> sa: (B, 12, H, W, 8) bf16  (8-ch chunk planes).
// (R5-proven: ~107 us. Unchanged.)
// ---------------------------------------------------------------------------
__global__ __launch_bounds__(256) void sa_kernel(const float* __restrict__ x,
                                                 const float* __restrict__ pf,
                                                 unsigned short* __restrict__ sa) {
    int bid   = blockIdx.x;
    int patch = bid % P_;
    int b     = bid / P_;
    int gh = patch / GW_, gw = patch % GW_;
    int t  = threadIdx.x;
    int py = t >> 4, px = t & 15;
    int y  = gh * 16 + py, xx = gw * 16 + px;

    __shared__ float xs[2][8][256];    // 16 KB double-buffered x slice

    const float* xp0 = x + (size_t)b * C_ * HW_ + (size_t)y * W_ + xx;

    float lf[8];
    #pragma unroll
    for (int ch = 0; ch < 8; ++ch) lf[ch] = xp0[(size_t)ch * HW_];

    for (int cc = 0; cc < NCH_; ++cc) {
        int buf = cc & 1;
        #pragma unroll
        for (int ch = 0; ch < 8; ++ch) xs[buf][ch][t] = lf[ch];
        __syncthreads();
        if (cc < NCH_ - 1) {
            #pragma unroll
            for (int ch = 0; ch < 8; ++ch)
                lf[ch] = xp0[(size_t)((cc + 1) * 8 + ch) * HW_];
        }

        ushort8 v;
        #pragma unroll
        for (int ch = 0; ch < 8; ++ch) {
            const float* wgt = pf + ((size_t)(cc * 8 + ch) * P_ + patch) * 9;  // uniform -> s_load
            float a = 0.f;
            #pragma unroll
            for (int dy = -1; dy <= 1; ++dy) {
                int yy = py + dy;
                if ((unsigned)yy < 16u) {
                    #pragma unroll
                    for (int dx = -1; dx <= 1; ++dx) {
                        int xq = px + dx;
                        if ((unsigned)xq < 16u)
                            a = fmaf(xs[buf][ch][yy * 16 + xq],
                                     wgt[(dy + 1) * 3 + (dx + 1)], a);
                    }
                }
            }
            v[ch] = f2bf(a);
        }
        *(ushort8*)&sa[(((size_t)(b * NCH_ + cc) * H_ + y) * W_ + xx) * 8] = v;
    }
}

// ---------------------------------------------------------------------------
// Kernel 2: implicit-GEMM MFMA conv (M=256 px, N=96, K=864) + exact GELU.
// R9 = R6's measured-best structure (52 KB dbuf A tile, stride-40 pad,
// B from global, full 9-tap unroll, 1 barrier/group) with the work split
// across 512 threads / 8 waves: wave = (wm 0..3 in M) x (wn 0..1 in N).
// Per-thread acc[4][3] = 48 VGPR -> fits 128-reg cap -> 4 waves/SIMD.
// ---------------------------------------------------------------------------
__global__ __launch_bounds__(512, 4) void conv2_mfma(const unsigned short* __restrict__ sa,
                                                     const unsigned short* __restrict__ ofb,
                                                     float* __restrict__ out) {
    // XCD-aware swizzle (3136 % 8 == 0 -> bijective)
    int bid0 = blockIdx.x;
    int bid  = (bid0 % 8) * (3136 / 8) + bid0 / 8;
    int patch = bid % P_;
    int b     = bid / P_;
    int gh = patch / GW_, gw = patch % GW_;
    int y0 = gh * 16, x0 = gw * 16;

    int t = threadIdx.x;
    int w = t >> 6, l = t & 63;
    int wm = w & 3, wn = w >> 2;            // 4 M-waves x 2 N-waves
    int mrow = l & 15, kgrp = l >> 4;

    __shared__ ushort8 at8[2][1620];        // 2 x 324 px x 40 ushort = 51840 B

    ushort8 rA[3];                          // staged tile in flight (12 VGPR)

    auto LOADG = [&](int g) {
        #pragma unroll
        for (int i = 0; i < 3; ++i) {
            int v = t + i * 512;            // 1296 tasks = 4 chunk-planes x 324 px
            if (v < 1296) {
                int ccl = v / 324, hpx = v % 324;
                int gy = y0 - 1 + hpx / 18, gx = x0 - 1 + hpx % 18;
                ushort8 val = {0, 0, 0, 0, 0, 0, 0, 0};
                if ((unsigned)gy < (unsigned)H_ && (unsigned)gx < (unsigned)W_)
                    val = *(const ushort8*)&sa[(((size_t)(b * NCH_ + g * 4 + ccl) * H_ + gy)
                                               * W_ + gx) * 8];
                rA[i] = val;
            }
        }
    };
    auto WRITEG = [&](int g) {
        unsigned short* atw = (unsigned short*)at8[g & 1];
        #pragma unroll
        for (int i = 0; i < 3; ++i) {
            int v = t + i * 512;
            if (v < 1296) {
                int ccl = v / 324, hpx = v % 324;
                *(ushort8*)&atw[hpx * 40 + ccl * 8] = rA[i];
            }
        }
    };

    f32x4 acc[4][3];
    #pragma unroll
    for (int mi = 0; mi < 4; ++mi)
        #pragma unroll
        for (int ni = 0; ni < 3; ++ni)
            acc[mi][ni] = (f32x4)0.f;

    LOADG(0);
    #pragma unroll 1
    for (int g = 0; g < 3; ++g) {
        WRITEG(g);                          // waits (auto vmcnt) on LOADG(g)
        __syncthreads();                    // tile g visible to all waves
        if (g < 2) LOADG(g + 1);            // next loads in flight across MFMA window
        const unsigned short* atg = (const unsigned short*)at8[g & 1];

        #pragma unroll                      // full unroll: big scheduling window
        for (int tap = 0; tap < 9; ++tap) {
            int ky = tap / 3, kx = tap % 3;
            short8 af[4];
            #pragma unroll
            for (int mi = 0; mi < 4; ++mi)
                af[mi] = *(const short8*)&atg[((wm * 4 + mi + ky) * 18 + kx + mrow) * 40
                                              + kgrp * 8];
            const unsigned short* bofs = ofb + tap * (96 * 96) + (size_t)wn * 48 * 96
                                         + g * 32 + kgrp * 8;
            #pragma unroll
            for (int ni = 0; ni < 3; ++ni) {
                short8 bf = *(const short8*)&bofs[(ni * 16 + mrow) * 96];
                #pragma unroll
                for (int mi = 0; mi < 4; ++mi)
                    acc[mi][ni] = __builtin_amdgcn_mfma_f32_16x16x32_bf16(
                        af[mi], bf, acc[mi][ni], 0, 0, 0);
            }
        }
    }

    // ---- epilogue: exact GELU + f32x4 stores ----
    #pragma unroll
    for (int mi = 0; mi < 4; ++mi) {
        int gy = y0 + wm * 4 + mi;
        #pragma unroll
        for (int ni = 0; ni < 3; ++ni) {
            int cout = wn * 48 + ni * 16 + mrow;
            f32x4 gv;
            #pragma unroll
            for (int j = 0; j < 4; ++j) {
                float vv = acc[mi][ni][j];
                gv[j] = 0.5f * vv * (1.0f + erff(vv * 0.70710678118f));
            }
            *(f32x4*)&out[((size_t)b * COUT_ + cout) * HW_ + (size_t)gy * W_ +
                          x0 + kgrp * 4] = gv;
        }
    }
}

extern "C" void kernel_launch(void* const* d_in, const int* in_sizes, int n_in,
                              void* d_out, int out_size, void* d_ws, size_t ws_size,
                              hipStream_t stream) {
    const float* x  = (const float*)d_in[0];
    const float* pf = (const float*)d_in[1];
    const float* of = (const float*)d_in[2];
    float* out = (float*)d_out;

    unsigned short* sa  = (unsigned short*)d_ws;                       // 154,140,672 B
    unsigned short* ofb = (unsigned short*)((char*)d_ws + 154140672);  // + 165,888 B

    prep_ofb<<<324, 256, 0, stream>>>(of, ofb);
    sa_kernel<<<B_ * P_, 256, 0, stream>>>(x, pf, sa);
    conv2_mfma<<<B_ * P_, 512, 0, stream>>>(sa, ofb, out);
}

// Round 10
// 441.374 us; speedup vs baseline: 3.0577x; 1.2106x over previous
//
#include <hip/hip_runtime.h>
#include <hip/hip_bf16.h>

#define B_    16
#define C_    96
#define H_    224
#define W_    224
#define COUT_ 96
#define GH_   14
#define GW_   14
#define P_    196          // GH_*GW_
#define HW_   (H_*W_)      // 50176
#define NCH_  12           // 8-channel chunks

#define AS1 __attribute__((address_space(1)))
#define AS3 __attribute__((address_space(3)))

typedef __attribute__((ext_vector_type(8))) unsigned short ushort8;
typedef __attribute__((ext_vector_type(8))) short        short8;   // MFMA bf16x8 operand
typedef __attribute__((ext_vector_type(4))) float        f32x4;

__device__ __forceinline__ unsigned short f2bf(float f) {
    union { __hip_bfloat16 h; unsigned short u; } cv;
    cv.h = __float2bfloat16(f);
    return cv.u;
}

// ---------------------------------------------------------------------------
// Kernel 0: of (COUT,C,3,3) f32 -> ofb[tap][cout][c] bf16; also zero the
// 256 B zero-page used by conv2's OOB halo loads.
// ---------------------------------------------------------------------------
__global__ __launch_bounds__(256) void prep_ofb(const float* __restrict__ of,
                                                unsigned short* __restrict__ ofb,
                                                unsigned short* __restrict__ zp) {
    if (blockIdx.x == 0 && threadIdx.x < 128) zp[threadIdx.x] = 0;
    int idx = blockIdx.x * 256 + threadIdx.x;      // 9*96*96 = 82944
    if (idx < 9 * 96 * 96) {
        int tap = idx / (96 * 96);
        int r   = idx % (96 * 96);
        int cout = r / 96, c = r % 96;
        ofb[idx] = f2bf(of[((size_t)cout * 96 + c) * 9 + tap]);
    }
}

// ---------------------------------------------------------------------------
// Kernel 1: per-patch depthwise 3x3 (patch-local zero padding).
// x: (B,C,H,W) f32 -> sa: (B, 12, H, W, 8) bf16  (8-ch chunk planes).
// (R5-proven: ~107 us. Unchanged.)
// ---------------------------------------------------------------------------
__global__ __launch_bounds__(256) void sa_kernel(const float* __restrict__ x,
                                                 const float* __restrict__ pf,
                                                 unsigned short* __restrict__ sa) {
    int bid   = blockIdx.x;
    int patch = bid % P_;
    int b     = bid / P_;
    int gh = patch / GW_, gw = patch % GW_;
    int t  = threadIdx.x;
    int py = t >> 4, px = t & 15;
    int y  = gh * 16 + py, xx = gw * 16 + px;

    __shared__ float xs[2][8][256];    // 16 KB double-buffered x slice

    const float* xp0 = x + (size_t)b * C_ * HW_ + (size_t)y * W_ + xx;

    float lf[8];
    #pragma unroll
    for (int ch = 0; ch < 8; ++ch) lf[ch] = xp0[(size_t)ch * HW_];

    for (int cc = 0; cc < NCH_; ++cc) {
        int buf = cc & 1;
        #pragma unroll
        for (int ch = 0; ch < 8; ++ch) xs[buf][ch][t] = lf[ch];
        __syncthreads();
        if (cc < NCH_ - 1) {
            #pragma unroll
            for (int ch = 0; ch < 8; ++ch)
                lf[ch] = xp0[(size_t)((cc + 1) * 8 + ch) * HW_];
        }

        ushort8 v;
        #pragma unroll
        for (int ch = 0; ch < 8; ++ch) {
            const float* wgt = pf + ((size_t)(cc * 8 + ch) * P_ + patch) * 9;  // uniform -> s_load
            float a = 0.f;
            #pragma unroll
            for (int dy = -1; dy <= 1; ++dy) {
                int yy = py + dy;
                if ((unsigned)yy < 16u) {
                    #pragma unroll
                    for (int dx = -1; dx <= 1; ++dx) {
                        int xq = px + dx;
                        if ((unsigned)xq < 16u)
                            a = fmaf(xs[buf][ch][yy * 16 + xq],
                                     wgt[(dy + 1) * 3 + (dx + 1)], a);
                    }
                }
            }
            v[ch] = f2bf(a);
        }
        *(ushort8*)&sa[(((size_t)(b * NCH_ + cc) * H_ + y) * W_ + xx) * 8] = v;
    }
}

// ---------------------------------------------------------------------------
// Kernel 2: implicit-GEMM MFMA conv (M=256 px, N=96, K=864) + exact GELU.
// R10: 512 thr / 8 waves (4M x 2N), acc[4][3]=48 AGPR.
// A-tile staged via global_load_lds (width 16) -> ZERO arch-VGPR staging:
//   LDS layout [buf][ccl*324 + hpx] ushort8, linear in lane order (required);
//   OOB halo lanes read a zero-page (all lanes always issue; no exec masks);
//   tasks 1296..1535 land in a trash pad so per-wave issue count is uniform.
// Double-buffered (2 x 24 KB); one __syncthreads per group = the vmcnt drain.
// ---------------------------------------------------------------------------
__global__ __launch_bounds__(512, 4) void conv2_mfma(const unsigned short* __restrict__ sa,
                                                     const unsigned short* __restrict__ ofb,
                                                     const unsigned short* __restrict__ zp,
                                                     float* __restrict__ out) {
    // XCD-aware swizzle (3136 % 8 == 0 -> bijective)
    int bid0 = blockIdx.x;
    int bid  = (bid0 % 8) * (3136 / 8) + bid0 / 8;
    int patch = bid % P_;
    int b     = bid / P_;
    int gh = patch / GW_, gw = patch % GW_;
    int y0 = gh * 16, x0 = gw * 16;

    int t = threadIdx.x;
    int w = t >> 6, l = t & 63;
    int wm = w & 3, wn = w >> 2;            // 4 M-waves x 2 N-waves
    int mrow = l & 15, kgrp = l >> 4;

    __shared__ ushort8 at8[2][1536];        // 2 x (1296 tile + 240 trash) x 16 B = 49152 B

    // issue one group's A-halo loads straight to LDS (no VGPR round-trip)
    auto STAGE = [&](int g) {
        int buf = g & 1;
        #pragma unroll
        for (int i = 0; i < 3; ++i) {
            int v = t + i * 512;            // 0..1535; [0,1296) = real tasks
            const unsigned short* src = zp;
            if (v < 1296) {
                int ccl = v / 324, hpx = v - ccl * 324;
                int gy = y0 - 1 + hpx / 18, gx = x0 - 1 + hpx % 18;
                if ((unsigned)gy < (unsigned)H_ && (unsigned)gx < (unsigned)W_)
                    src = &sa[(((size_t)(b * NCH_ + g * 4 + ccl) * H_ + gy) * W_ + gx) * 8];
            }
            __builtin_amdgcn_global_load_lds((const AS1 unsigned int*)src,
                                             (AS3 unsigned int*)&at8[buf][v], 16, 0, 0);
        }
    };

    f32x4 acc[4][3];
    #pragma unroll
    for (int mi = 0; mi < 4; ++mi)
        #pragma unroll
        for (int ni = 0; ni < 3; ++ni)
            acc[mi][ni] = (f32x4)0.f;

    STAGE(0);
    #pragma unroll 1
    for (int g = 0; g < 3; ++g) {
        __syncthreads();                    // vmcnt(0) drain: buf g complete + visible
        if (g < 2) STAGE(g + 1);            // next tile in flight across MFMA phase
        const unsigned short* atg = (const unsigned short*)at8[g & 1];

        #pragma unroll                      // 108-MFMA scheduling window per group
        for (int tap = 0; tap < 9; ++tap) {
            int ky = tap / 3, kx = tap % 3;
            const unsigned short* bofs = ofb + tap * (96 * 96) + wn * 48 * 96
                                         + g * 32 + kgrp * 8;
            short8 bf[3];
            #pragma unroll
            for (int ni = 0; ni < 3; ++ni)
                bf[ni] = *(const short8*)&bofs[(ni * 16 + mrow) * 96];
            #pragma unroll
            for (int mi = 0; mi < 4; ++mi) {
                short8 af = *(const short8*)&atg[(kgrp * 324 + (wm * 4 + mi + ky) * 18
                                                 + kx + mrow) * 8];
                #pragma unroll
                for (int ni = 0; ni < 3; ++ni)
                    acc[mi][ni] = __builtin_amdgcn_mfma_f32_16x16x32_bf16(
                        af, bf[ni], acc[mi][ni], 0, 0, 0);
            }
        }
    }

    // ---- epilogue: exact GELU + f32x4 stores ----
    #pragma unroll
    for (int mi = 0; mi < 4; ++mi) {
        int gy = y0 + wm * 4 + mi;
        #pragma unroll
        for (int ni = 0; ni < 3; ++ni) {
            int cout = wn * 48 + ni * 16 + mrow;
            f32x4 gv;
            #pragma unroll
            for (int j = 0; j < 4; ++j) {
                float vv = acc[mi][ni][j];
                gv[j] = 0.5f * vv * (1.0f + erff(vv * 0.70710678118f));
            }
            *(f32x4*)&out[((size_t)b * COUT_ + cout) * HW_ + (size_t)gy * W_ +
                          x0 + kgrp * 4] = gv;
        }
    }
}

extern "C" void kernel_launch(void* const* d_in, const int* in_sizes, int n_in,
                              void* d_out, int out_size, void* d_ws, size_t ws_size,
                              hipStream_t stream) {
    const float* x  = (const float*)d_in[0];
    const float* pf = (const float*)d_in[1];
    const float* of = (const float*)d_in[2];
    float* out = (float*)d_out;

    unsigned short* sa  = (unsigned short*)d_ws;                       // 154,140,672 B
    unsigned short* ofb = (unsigned short*)((char*)d_ws + 154140672);  // + 165,888 B
    unsigned short* zp  = (unsigned short*)((char*)d_ws + 154306560);  // + 256 B zero-page

    prep_ofb<<<324, 256, 0, stream>>>(of, ofb, zp);
    sa_kernel<<<B_ * P_, 256, 0, stream>>>(x, pf, sa);
    conv2_mfma<<<B_ * P_, 512, 0, stream>>>(sa, ofb, zp, out);
}

// Round 11
// 406.891 us; speedup vs baseline: 3.3169x; 1.0847x over previous
//
#include <hip/hip_runtime.h>
#include <hip/hip_bf16.h>

#define B_    16
#define C_    96
#define H_    224
#define W_    224
#define COUT_ 96
#define GH_   14
#define GW_   14
#define P_    196          // GH_*GW_
#define HW_   (H_*W_)      // 50176
#define NCH_  12           // 8-channel chunks

#define AS1 __attribute__((address_space(1)))
#define AS3 __attribute__((address_space(3)))

typedef __attribute__((ext_vector_type(8))) unsigned short ushort8;
typedef __attribute__((ext_vector_type(8))) short        short8;   // MFMA bf16x8 operand
typedef __attribute__((ext_vector_type(4))) float        f32x4;

__device__ __forceinline__ unsigned short f2bf(float f) {
    union { __hip_bfloat16 h; unsigned short u; } cv;
    cv.h = __float2bfloat16(f);
    return cv.u;
}

// ---------------------------------------------------------------------------
// Kernel 0: of (COUT,C,3,3) f32 -> ofb[tap][cout][c] bf16; zero-page for OOB.
// ---------------------------------------------------------------------------
__global__ __launch_bounds__(256) void prep_ofb(const float* __restrict__ of,
                                                unsigned short* __restrict__ ofb,
                                                unsigned short* __restrict__ zp) {
    if (blockIdx.x == 0 && threadIdx.x < 128) zp[threadIdx.x] = 0;
    int idx = blockIdx.x * 256 + threadIdx.x;      // 9*96*96 = 82944
    if (idx < 9 * 96 * 96) {
        int tap = idx / (96 * 96);
        int r   = idx % (96 * 96);
        int cout = r / 96, c = r % 96;
        ofb[idx] = f2bf(of[((size_t)cout * 96 + c) * 9 + tap]);
    }
}

// ---------------------------------------------------------------------------
// Kernel 1: per-patch depthwise 3x3 (patch-local zero padding).
// x: (B,C,H,W) f32 -> sa: (B, 12, H, W, 8) bf16  (8-ch chunk planes).
// (R5-proven: ~107 us. Unchanged.)
// ---------------------------------------------------------------------------
__global__ __launch_bounds__(256) void sa_kernel(const float* __restrict__ x,
                                                 const float* __restrict__ pf,
                                                 unsigned short* __restrict__ sa) {
    int bid   = blockIdx.x;
    int patch = bid % P_;
    int b     = bid / P_;
    int gh = patch / GW_, gw = patch % GW_;
    int t  = threadIdx.x;
    int py = t >> 4, px = t & 15;
    int y  = gh * 16 + py, xx = gw * 16 + px;

    __shared__ float xs[2][8][256];    // 16 KB double-buffered x slice

    const float* xp0 = x + (size_t)b * C_ * HW_ + (size_t)y * W_ + xx;

    float lf[8];
    #pragma unroll
    for (int ch = 0; ch < 8; ++ch) lf[ch] = xp0[(size_t)ch * HW_];

    for (int cc = 0; cc < NCH_; ++cc) {
        int buf = cc & 1;
        #pragma unroll
        for (int ch = 0; ch < 8; ++ch) xs[buf][ch][t] = lf[ch];
        __syncthreads();
        if (cc < NCH_ - 1) {
            #pragma unroll
            for (int ch = 0; ch < 8; ++ch)
                lf[ch] = xp0[(size_t)((cc + 1) * 8 + ch) * HW_];
        }

        ushort8 v;
        #pragma unroll
        for (int ch = 0; ch < 8; ++ch) {
            const float* wgt = pf + ((size_t)(cc * 8 + ch) * P_ + patch) * 9;  // uniform -> s_load
            float a = 0.f;
            #pragma unroll
            for (int dy = -1; dy <= 1; ++dy) {
                int yy = py + dy;
                if ((unsigned)yy < 16u) {
                    #pragma unroll
                    for (int dx = -1; dx <= 1; ++dx) {
                        int xq = px + dx;
                        if ((unsigned)xq < 16u)
                            a = fmaf(xs[buf][ch][yy * 16 + xq],
                                     wgt[(dy + 1) * 3 + (dx + 1)], a);
                    }
                }
            }
            v[ch] = f2bf(a);
        }
        *(ushort8*)&sa[(((size_t)(b * NCH_ + cc) * H_ + y) * W_ + xx) * 8] = v;
    }
}

// ---------------------------------------------------------------------------
// Kernel 2: implicit-GEMM MFMA conv + exact GELU, HALF-PATCH blocks.
// Block = 8x16 px (half a patch) x 96 couts; 256 thr / 4 waves (2M x 2N).
// Wave = 64 px x 48 couts -> acc[4][3] = 48 AGPR (proven shape).
// A: 10x18 halo, 4 planes [ccl][180] ushort8 via global_load_lds (zero
//    arch-VGPR staging), double-buffered 2x12 KB, 1 barrier per group.
// B: from global/L2; launch_bounds(256,3) -> ~120 arch regs so the full
//    9-tap unroll can prefetch bf[] taps ahead (the R10 bottleneck).
// ---------------------------------------------------------------------------
__global__ __launch_bounds__(256, 3) void conv2_mfma(const unsigned short* __restrict__ sa,
                                                     const unsigned short* __restrict__ ofb,
                                                     const unsigned short* __restrict__ zp,
                                                     float* __restrict__ out) {
    // XCD-aware swizzle (6272 % 8 == 0 -> bijective); logical-contiguous
    // blocks = (b, patch, half) order -> same-patch halves share L2 halo.
    int bid0 = blockIdx.x;
    int bid  = (bid0 % 8) * (6272 / 8) + bid0 / 8;
    int half = bid & 1;
    int pid  = bid >> 1;
    int patch = pid % P_;
    int b     = pid / P_;
    int gh = patch / GW_, gw = patch % GW_;
    int y0 = gh * 16 + half * 8, x0 = gw * 16;   // 8x16 output region

    int t = threadIdx.x;
    int w = t >> 6, l = t & 63;
    int wm = w & 1, wn = w >> 1;            // 2 M-waves x 2 N-waves
    int mrow = l & 15, kgrp = l >> 4;

    __shared__ ushort8 at8[2][768];         // 2 x (720 tile + 48 trash) x 16 B = 24576 B

    // stage one 32-ch group's 10x18 halo straight to LDS (no VGPR round-trip)
    auto STAGE = [&](int g) {
        int buf = g & 1;
        #pragma unroll
        for (int i = 0; i < 3; ++i) {
            int v = t + i * 256;            // 0..767; [0,720) = real tasks
            const unsigned short* src = zp;
            if (v < 720) {
                int ccl = v / 180, hpx = v - ccl * 180;
                int gy = y0 - 1 + hpx / 18, gx = x0 - 1 + hpx % 18;
                if ((unsigned)gy < (unsigned)H_ && (unsigned)gx < (unsigned)W_)
                    src = &sa[(((size_t)(b * NCH_ + g * 4 + ccl) * H_ + gy) * W_ + gx) * 8];
            }
            __builtin_amdgcn_global_load_lds((const AS1 unsigned int*)src,
                                             (AS3 unsigned int*)&at8[buf][v], 16, 0, 0);
        }
    };

    f32x4 acc[4][3];
    #pragma unroll
    for (int mi = 0; mi < 4; ++mi)
        #pragma unroll
        for (int ni = 0; ni < 3; ++ni)
            acc[mi][ni] = (f32x4)0.f;

    STAGE(0);
    #pragma unroll 1
    for (int g = 0; g < 3; ++g) {
        __syncthreads();                    // vmcnt(0) drain: buf g complete + visible
        if (g < 2) STAGE(g + 1);            // next tile in flight across MFMA phase
        const unsigned short* atg = (const unsigned short*)at8[g & 1];

        #pragma unroll                      // full unroll: big scheduling window
        for (int tap = 0; tap < 9; ++tap) {
            int ky = tap / 3, kx = tap % 3;
            const unsigned short* bofs = ofb + tap * (96 * 96) + (wn * 48) * 96
                                         + g * 32 + kgrp * 8;
            short8 bf[3];
            #pragma unroll
            for (int ni = 0; ni < 3; ++ni)
                bf[ni] = *(const short8*)&bofs[(ni * 16 + mrow) * 96];
            #pragma unroll
            for (int mi = 0; mi < 4; ++mi) {
                short8 af = *(const short8*)&atg[(kgrp * 180 + (wm * 4 + mi + ky) * 18
                                                 + kx + mrow) * 8];
                #pragma unroll
                for (int ni = 0; ni < 3; ++ni)
                    acc[mi][ni] = __builtin_amdgcn_mfma_f32_16x16x32_bf16(
                        af, bf[ni], acc[mi][ni], 0, 0, 0);
            }
        }
    }

    // ---- epilogue: exact GELU + f32x4 stores ----
    #pragma unroll
    for (int mi = 0; mi < 4; ++mi) {
        int gy = y0 + wm * 4 + mi;
        #pragma unroll
        for (int ni = 0; ni < 3; ++ni) {
            int cout = wn * 48 + ni * 16 + mrow;
            f32x4 gv;
            #pragma unroll
            for (int j = 0; j < 4; ++j) {
                float vv = acc[mi][ni][j];
                gv[j] = 0.5f * vv * (1.0f + erff(vv * 0.70710678118f));
            }
            *(f32x4*)&out[((size_t)b * COUT_ + cout) * HW_ + (size_t)gy * W_ +
                          x0 + kgrp * 4] = gv;
        }
    }
}

extern "C" void kernel_launch(void* const* d_in, const int* in_sizes, int n_in,
                              void* d_out, int out_size, void* d_ws, size_t ws_size,
                              hipStream_t stream) {
    const float* x  = (const float*)d_in[0];
    const float* pf = (const float*)d_in[1];
    const float* of = (const float*)d_in[2];
    float* out = (float*)d_out;

    unsigned short* sa  = (unsigned short*)d_ws;                       // 154,140,672 B
    unsigned short* ofb = (unsigned short*)((char*)d_ws + 154140672);  // + 165,888 B
    unsigned short* zp  = (unsigned short*)((char*)d_ws + 154306560);  // + 256 B zero-page

    prep_ofb<<<324, 256, 0, stream>>>(of, ofb, zp);
    sa_kernel<<<B_ * P_, 256, 0, stream>>>(x, pf, sa);
    conv2_mfma<<<B_ * P_ * 2, 256, 0, stream>>>(sa, ofb, zp, out);
}